// Round 10
// baseline (7259.373 us; speedup 1.0000x reference)
//
#include <hip/hip_runtime.h>
#include <hip/hip_fp16.h>
#include <math.h>

// ---------------------------------------------------------------------------
// RNN: h_{t+1} = relu(x_t @ W_in^T + h_t @ W_hh^T + b_hh + noise_t*scale)
// outputs: hidden_list [128,256,1024] f32, output_list [128,256,128] f32,
//          h_final [128,1024] f32 (concatenated flat in d_out)
//
// R10 = R9 exchange (XCD-striped roles, sc0 L2-served spin + sys-scope
// escalation, tag-in-data) + DIRECT-TO-VGPR A-fragments:
//  - R9 counters: FETCH collapsed 298->59.6MB (L2 fast path works) but time
//    ~unchanged -> residual = LDS phase (~4300cy of 7150cy step: 288
//    ds_read_b128 + staging + conflicts + 2 barriers).
//  - Fix: each lane's MFMA A-frag is a contiguous dwordx4 of h (row l15,
//    halves ki*32+lk*8): load ALL 32 per lane directly to VGPRs (batched
//    sc0 loads, one vmcnt), tag-validate in regs, feed MFMA directly.
//    htile deleted; staging deleted; av reads deleted; NO barriers in loop.
//  - Sign trick: tag bit == fp16 sign bit and relu(h)>=0, so a fully-tagged
//    tile is exactly -h. Validation guarantees uniform tags -> accumulate
//    h-part in its own acc and apply +/-1 per step. No stripping VALU.
//  - W: all 32 chunks in LDS (64x1024 fp16 = 128KB, XOR-swizzled granules).
//    bv reads: 32/wave (was 60+writes). x-chunks stay in regs.
//  - Escalation: rounds 0..7 sc0 (L2); rounds 8+ sc0+sc1 (bypass L2,
//    coherence point) -> progress under ANY blockIdx->XCD mapping.
//  - WAR safety at wave granularity: every wave reads full K=1024 of h(t)
//    before it can publish its h(t+1) slice; h(t+2) writers need all of
//    h(t+1) -> transitively all slot-t reads complete. Gen-tag ring as R5-R9.
// ---------------------------------------------------------------------------

typedef _Float16 half8 __attribute__((ext_vector_type(8)));
typedef float    f32x4 __attribute__((ext_vector_type(4)));
typedef unsigned int u32x4 __attribute__((ext_vector_type(4)));
typedef unsigned long long u64;

#define SIGMA_F 0.05f

constexpr int T_  = 256;
constexpr int B_  = 128;
constexpr int NH  = 1024;
constexpr int NIN = 128;
constexpr int MB  = 16;           // batch rows per group

// workspace layout (bytes)
constexpr size_t OFF_XT  = 0;                            // fp16 [T][B][NIN] 8.39MB
constexpr size_t OFF_NB  = (size_t)T_*B_*NIN*2;          // f32  [T][NH]     1.05MB
constexpr size_t OFF_WO  = OFF_NB + (size_t)T_*NH*4;     // fp16 [NIN][NH]   0.26MB
constexpr size_t OFF_HB  = OFF_WO + (size_t)NIN*NH*2;    // u32 [2][B][512]  0.52MB

__device__ __forceinline__ unsigned short f16bits(float v) {
    return __half_as_ushort(__float2half(v));
}
__device__ __forceinline__ void ast(unsigned int* p, unsigned int v) {
    __hip_atomic_store(p, v, __ATOMIC_RELAXED, __HIP_MEMORY_SCOPE_AGENT);
}

// 8 dwordx4 loads from one 64-bit base with literal offsets. FLAGS: cache
// scope. TAIL: optional trailing waitcnt.
#define LD8G(r, p, O0,O1,O2,O3,O4,O5,O6,O7, FLAGS, TAIL)                    \
  asm volatile(                                                             \
    "global_load_dwordx4 %0, %8, off offset:" #O0 " " FLAGS "\n\t"          \
    "global_load_dwordx4 %1, %8, off offset:" #O1 " " FLAGS "\n\t"          \
    "global_load_dwordx4 %2, %8, off offset:" #O2 " " FLAGS "\n\t"          \
    "global_load_dwordx4 %3, %8, off offset:" #O3 " " FLAGS "\n\t"          \
    "global_load_dwordx4 %4, %8, off offset:" #O4 " " FLAGS "\n\t"          \
    "global_load_dwordx4 %5, %8, off offset:" #O5 " " FLAGS "\n\t"          \
    "global_load_dwordx4 %6, %8, off offset:" #O6 " " FLAGS "\n\t"          \
    "global_load_dwordx4 %7, %8, off offset:" #O7 " " FLAGS TAIL            \
    : "=&v"((r)[0]), "=&v"((r)[1]), "=&v"((r)[2]), "=&v"((r)[3]),           \
      "=&v"((r)[4]), "=&v"((r)[5]), "=&v"((r)[6]), "=&v"((r)[7])            \
    : "v"(p) : "memory")

__device__ __forceinline__ void ld32_sc0(u32x4 q[32], const unsigned int* p) {
    LD8G(q +  0, p,    0,   64,  128,  192,  256,  320,  384,  448, "sc0", "\n\t");
    LD8G(q +  8, p,  512,  576,  640,  704,  768,  832,  896,  960, "sc0", "\n\t");
    LD8G(q + 16, p, 1024, 1088, 1152, 1216, 1280, 1344, 1408, 1472, "sc0", "\n\t");
    LD8G(q + 24, p, 1536, 1600, 1664, 1728, 1792, 1856, 1920, 1984, "sc0",
         "\n\ts_waitcnt vmcnt(0)");
    __builtin_amdgcn_sched_barrier(0);
}
// escalation: bypass L2 (sc0 sc1) -> read from device coherence point
__device__ __forceinline__ void ld32_sys(u32x4 q[32], const unsigned int* p) {
    LD8G(q +  0, p,    0,   64,  128,  192,  256,  320,  384,  448, "sc0 sc1", "\n\t");
    LD8G(q +  8, p,  512,  576,  640,  704,  768,  832,  896,  960, "sc0 sc1", "\n\t");
    LD8G(q + 16, p, 1024, 1088, 1152, 1216, 1280, 1344, 1408, 1472, "sc0 sc1", "\n\t");
    LD8G(q + 24, p, 1536, 1600, 1664, 1728, 1792, 1856, 1920, 1984, "sc0 sc1",
         "\n\ts_waitcnt vmcnt(0)");
    __builtin_amdgcn_sched_barrier(0);
}

// ---------------------------------------------------------------------------
__global__ void setup_kernel(const float* __restrict__ X,
                             const float* __restrict__ hidden,
                             const float* __restrict__ b_hh,
                             const float* __restrict__ W_out,
                             const float* __restrict__ alpha_w,
                             const float* __restrict__ noise,
                             unsigned short* __restrict__ Xt,
                             float* __restrict__ NB,
                             unsigned short* __restrict__ Wo,
                             unsigned int* __restrict__ Hb0,
                             unsigned int* __restrict__ Hb1)
{
    int idx = blockIdx.x * 256 + threadIdx.x;
    // X [B][T][NIN] -> Xt [T][B][NIN] fp16
    if (idx < B_ * T_ * NIN) {
        int d = idx & 127, rest = idx >> 7;
        int brow = rest & 127, t = rest >> 7;
        Xt[idx] = f16bits(X[((size_t)brow * T_ + t) * NIN + d]);
    }
    if (idx < T_ * NH) {
        int c = idx & (NH - 1);
        NB[idx] = b_hh[c] + noise[idx] * (sqrtf(2.0f / alpha_w[c]) * SIGMA_F);
    }
    if (idx < NIN * NH) Wo[idx] = f16bits(W_out[idx]);
    if (idx < B_ * NH / 2) {
        // slot0 = initial h with gen-0 tag (0); slot1 = poison (tag 1)
        unsigned int lo = f16bits(hidden[idx * 2]);
        unsigned int hi = f16bits(hidden[idx * 2 + 1]);
        Hb0[idx] = (lo | (hi << 16)) & 0x7FFF7FFFu;
        Hb1[idx] = 0x80008000u;
    }
}

// ---------------------------------------------------------------------------
// Persistent RNN: 128 blocks x 256 threads (4 waves, 1 block/CU, no barriers
// in the time loop). Roles: m = bx&7 (XCD-striped), n = bx>>3 (col slice).
__global__ __launch_bounds__(256, 1) void rnn_step_kernel(
    const float* __restrict__ W_hh, const float* __restrict__ W_in,
    const unsigned short* __restrict__ Xt, const float* __restrict__ NB,
    unsigned int* __restrict__ Hb0, unsigned int* __restrict__ Hb1,
    float* __restrict__ hidden_list, float* __restrict__ h_final)
{
    __shared__ unsigned short wtile[64 * 1024];   // 131,072 B: all 32 chunks

    const int tid = threadIdx.x;
    const int m = blockIdx.x & 7;    // batch group (XCD-striped)
    const int n = blockIdx.x >> 3;   // column slice

    // ---- stage full W slice into LDS (XOR-swizzled 16B granules) ----
    for (int g = tid; g < 64 * 128; g += 256) {
        int row = g >> 7, G = g & 127;
        const float* s = W_hh + (size_t)(n * 64 + row) * NH + G * 8;
        half8 h;
        #pragma unroll
        for (int j = 0; j < 8; ++j) h[j] = (_Float16)s[j];
        *(half8*)&wtile[row * 1024 + ((G ^ (row & 7)) << 3)] = h;
    }

    const int wave = tid >> 6, lane = tid & 63;
    const int l15 = lane & 15, lk = lane >> 4;
    const int rowA = m * MB + l15;          // batch row (A-frag row)
    const int colW = wave * 16 + l15;       // local W row / output col
    const int gcol = n * 64 + colW;         // global hidden col

    // ---- per-lane register B-fragments for the x-part (W_in, 4 chunks) ----
    auto cvt8 = [](const float* s) {
        half8 h;
        #pragma unroll
        for (int j = 0; j < 8; ++j) h[j] = (_Float16)s[j];
        return h;
    };
    half8 bx[4];
    #pragma unroll
    for (int kx = 0; kx < 4; ++kx)
        bx[kx] = cvt8(W_in + (size_t)gcol * NIN + kx * 32 + lk * 8);
    __syncthreads();   // wtile ready (the only barrier the loop depends on)

    auto xpart = [&](int t) -> f32x4 {
        f32x4 a = {0.f, 0.f, 0.f, 0.f};
        const half8* xp = (const half8*)(Xt + ((size_t)t * B_ + rowA) * NIN) + lk;
        #pragma unroll
        for (int kx = 0; kx < 4; ++kx)
            a = __builtin_amdgcn_mfma_f32_16x16x32_f16(xp[kx * 4], bx[kx], a, 0, 0, 0);
        return a;
    };

    f32x4 accx = xpart(0);

    for (int t = 0; t < T_; ++t) {
        // per-lane A-frag base: row rowA, k-offset lk*8 halves (u32 index lk*4)
        const unsigned int* hp = ((t & 1) ? Hb1 : Hb0)
                                 + (size_t)rowA * 512 + lk * 4;
        const bool tagset = ((t >> 1) & 1) != 0;
        const unsigned int e32 = tagset ? 0x80008000u : 0u;

        // ---- phase 1: direct-to-VGPR tagged spin (32 dwordx4, 1 vmcnt) ----
        u32x4 q[32];
        {
            int round = 0;
            for (;;) {
                if (round < 8) ld32_sc0(q, hp);
                else           ld32_sys(q, hp);
                u32x4 e4 = {e32, e32, e32, e32};
                u32x4 red4 = q[0] ^ e4;
                #pragma unroll
                for (int j = 1; j < 32; ++j) red4 |= q[j] ^ e4;
                unsigned int red = (red4[0] | red4[1] | red4[2] | red4[3]);
                if (!(red & 0x80008000u)) break;
                ++round;
                __builtin_amdgcn_s_sleep(1);
            }
        }

        // ---- phase 2: 32 MFMAs, A straight from regs (tag = sign bit;
        //      uniform per step, compensated below). 2 accs break the chain.
        f32x4 acc0 = {0.f, 0.f, 0.f, 0.f}, acc1 = {0.f, 0.f, 0.f, 0.f};
        #pragma unroll
        for (int ki = 0; ki < 32; ++ki) {
            int G = 4 * ki + lk;
            half8 bv = *(const half8*)&wtile[colW * 1024 + ((G ^ (colW & 7)) << 3)];
            half8 av = __builtin_bit_cast(half8, q[ki]);
            if (ki & 1) acc1 = __builtin_amdgcn_mfma_f32_16x16x32_f16(av, bv, acc1, 0, 0, 0);
            else        acc0 = __builtin_amdgcn_mfma_f32_16x16x32_f16(av, bv, acc0, 0, 0, 0);
        }

        // ---- bias+noise, sign-compensated combine, relu ----
        const float nb = NB[t * NH + gcol];
        const float sg = tagset ? -1.f : 1.f;
        float hv[4];
        #pragma unroll
        for (int r2 = 0; r2 < 4; ++r2) {
            float v = fmaf(sg, acc0[r2] + acc1[r2], accx[r2] + nb);
            hv[r2] = v > 0.f ? v : 0.f;
        }

        // ---- publish h_{t+1} FIRST (tag in-word; agent store writes
        //      through local L2 -> same-XCD sc0 pollers see it, L3 too) ----
        if (t < T_ - 1) {
            unsigned int* hn = (t & 1) ? Hb0 : Hb1;
            const unsigned int tagb = (((t + 1) >> 1) & 1) ? 0x80008000u : 0u;
            #pragma unroll
            for (int r2 = 0; r2 < 4; ++r2) {
                float other = __shfl_xor(hv[r2], 1);
                if (!(lane & 1)) {
                    unsigned int val = (unsigned int)f16bits(hv[r2]) |
                                       ((unsigned int)f16bits(other) << 16) | tagb;
                    int brow = m * MB + lk * 4 + r2;
                    ast(&hn[(size_t)brow * 512 + (gcol >> 1)], val);
                }
            }
        }

        // ---- off-critical-path: fp32 outputs, next x-part ----
        #pragma unroll
        for (int r2 = 0; r2 < 4; ++r2) {
            int brow = m * MB + lk * 4 + r2;
            hidden_list[((size_t)brow * T_ + t) * NH + gcol] = hv[r2];
        }
        if (t == T_ - 1) {
            #pragma unroll
            for (int r2 = 0; r2 < 4; ++r2) {
                int brow = m * MB + lk * 4 + r2;
                h_final[(size_t)brow * NH + gcol] = hv[r2];
            }
        } else {
            accx = xpart(t + 1);
        }
    }
}

// ---------------------------------------------------------------------------
// Readout: Y[32768,128] = HL[32768,1024](f32->f16) @ Wo^T(f16), fp32 out.
__global__ __launch_bounds__(256, 4) void ygemm_kernel(
    const float* __restrict__ HL, const unsigned short* __restrict__ Wo,
    float* __restrict__ Y)
{
    typedef unsigned short ushort8 __attribute__((ext_vector_type(8)));
    const int tid = threadIdx.x;
    const int wave = tid >> 6, lane = tid & 63;
    const int l15 = lane & 15, lk = lane >> 4;
    const size_t rowbase = (size_t)blockIdx.x * 64;

    f32x4 acc[4][2] = {};

    #pragma unroll 2
    for (int ki = 0; ki < 32; ++ki) {
        const int k0 = ki * 32 + lk * 8;
        half8 bfr[2];
        #pragma unroll
        for (int nt = 0; nt < 2; ++nt) {
            int ncol = (wave * 2 + nt) * 16 + l15;
            ushort8 braw = *(const ushort8*)(Wo + ncol * NH + k0);
            bfr[nt] = __builtin_bit_cast(half8, braw);
        }
        #pragma unroll
        for (int mt = 0; mt < 4; ++mt) {
            size_t row = rowbase + mt * 16 + l15;
            const float4* ap = (const float4*)(HL + row * NH + k0);
            float4 a0 = ap[0];
            float4 a1 = ap[1];
            half8 a = { (_Float16)a0.x, (_Float16)a0.y, (_Float16)a0.z, (_Float16)a0.w,
                        (_Float16)a1.x, (_Float16)a1.y, (_Float16)a1.z, (_Float16)a1.w };
            #pragma unroll
            for (int nt = 0; nt < 2; ++nt)
                acc[mt][nt] = __builtin_amdgcn_mfma_f32_16x16x32_f16(a, bfr[nt], acc[mt][nt], 0, 0, 0);
        }
    }

    #pragma unroll
    for (int mt = 0; mt < 4; ++mt) {
        #pragma unroll
        for (int nt = 0; nt < 2; ++nt) {
            int ncol = (wave * 2 + nt) * 16 + l15;
            #pragma unroll
            for (int r = 0; r < 4; ++r) {
                size_t row = rowbase + mt * 16 + lk * 4 + r;
                Y[row * NIN + ncol] = acc[mt][nt][r];
            }
        }
    }
}

// ---------------------------------------------------------------------------
extern "C" void kernel_launch(void* const* d_in, const int* in_sizes, int n_in,
                              void* d_out, int out_size, void* d_ws, size_t ws_size,
                              hipStream_t stream)
{
    const float* X      = (const float*)d_in[0];
    const float* hidden = (const float*)d_in[1];
    const float* W_in   = (const float*)d_in[2];
    const float* W_hh   = (const float*)d_in[3];
    const float* b_hh   = (const float*)d_in[4];
    const float* W_out  = (const float*)d_in[5];
    const float* alpha  = (const float*)d_in[6];
    const float* noise  = (const float*)d_in[7];

    char* ws = (char*)d_ws;   // ~10.2 MB
    unsigned short* Xt = (unsigned short*)(ws + OFF_XT);
    float*          NB = (float*)(ws + OFF_NB);
    unsigned short* Wo = (unsigned short*)(ws + OFF_WO);
    unsigned int*  Hb0 = (unsigned int*)(ws + OFF_HB);
    unsigned int*  Hb1 = Hb0 + (size_t)B_ * NH / 2;

    float* hidden_list = (float*)d_out;                                  // [128,256,1024]
    float* output_list = hidden_list + (size_t)B_ * T_ * NH;             // [128,256,128]
    float* h_final     = output_list + (size_t)B_ * T_ * NIN;            // [128,1024]

    setup_kernel<<<(B_ * T_ * NIN + 255) / 256, 256, 0, stream>>>(
        X, hidden, b_hh, W_out, alpha, noise, Xt, NB, Wo, Hb0, Hb1);

    rnn_step_kernel<<<128, 256, 0, stream>>>(
        W_hh, W_in, Xt, NB, Hb0, Hb1, hidden_list, h_final);

    ygemm_kernel<<<(B_ * T_) / 64, 256, 0, stream>>>(
        hidden_list, Wo, output_list);
}

// Round 11
// 1765.571 us; speedup vs baseline: 4.1116x; 4.1116x over previous
//
#include <hip/hip_runtime.h>
#include <hip/hip_fp16.h>
#include <math.h>

// ---------------------------------------------------------------------------
// RNN: h_{t+1} = relu(x_t @ W_in^T + h_t @ W_hh^T + b_hh + noise_t*scale)
// outputs: hidden_list [128,256,1024] f32, output_list [128,256,128] f32,
//          h_final [128,1024] f32 (concatenated flat in d_out)
//
// R11 = R9 exchange (proven: XCD-local L2 spin, FETCH 298->59MB) + HALVED
// per-block serial phase:
//  - R10 failed on VGPR spill (q[32]=128 VGPR live -> scratch, 7208us).
//    Reverted to R9 structure; registers bounded again (spin r[8]=32 VGPR).
//  - 256 blocks x 32 cols (8 groups x 32 slices). m=bx&7 XCD stripe: each
//    group's 32 blocks land on one XCD (round-robin heuristic; correctness
//    independent). All 256 CUs now active (R9 idled half).
//  - Block: 4 waves = 2 col-tiles x split-K-2. Per wave 16 av + 16 bv
//    ds_read_b128 (128/CU/step, half of R9's 256) + small f32x4 LDS reduce.
//  - Per-block publish/output stores halve (32 cols).
//  - hidden_list/h_final stores non-temporal (don't pollute L2 exchange).
//  - Spin: R9's escalation, threshold 3->6 rounds (sc0 fast path longer
//    before falling to L3-coherent agent loads; those stay for liveness
//    under ANY blockIdx->XCD mapping).
//  - Tag-in-data everywhere (relu(h)>=0 frees fp16 sign bits; gen tag
//    (t>>1)&1; 2-slot ring; WAR-safe by all-to-all dependence) -- proven
//    R3-R9.  LDS: wtile 64KB + htile 32KB + rtile 2KB = 98KB, 1 block/CU,
//    grid=256=CU count -> co-resident.
// ---------------------------------------------------------------------------

typedef _Float16 half8 __attribute__((ext_vector_type(8)));
typedef float    f32x4 __attribute__((ext_vector_type(4)));
typedef unsigned int u32x4 __attribute__((ext_vector_type(4)));
typedef unsigned long long u64;

#define SIGMA_F 0.05f

constexpr int T_  = 256;
constexpr int B_  = 128;
constexpr int NH  = 1024;
constexpr int NIN = 128;
constexpr int MB  = 16;           // batch rows per group
constexpr int NCB = 32;           // cols per block

// workspace layout (bytes)
constexpr size_t OFF_XT  = 0;                            // fp16 [T][B][NIN] 8.39MB
constexpr size_t OFF_NB  = (size_t)T_*B_*NIN*2;          // f32  [T][NH]     1.05MB
constexpr size_t OFF_WO  = OFF_NB + (size_t)T_*NH*4;     // fp16 [NIN][NH]   0.26MB
constexpr size_t OFF_HB  = OFF_WO + (size_t)NIN*NH*2;    // u32 [2][B][512]  0.52MB

__device__ __forceinline__ unsigned short f16bits(float v) {
    return __half_as_ushort(__float2half(v));
}
__device__ __forceinline__ u64 ald(const u64* p) {
    return __hip_atomic_load(p, __ATOMIC_RELAXED, __HIP_MEMORY_SCOPE_AGENT);
}
__device__ __forceinline__ void ast(unsigned int* p, unsigned int v) {
    __hip_atomic_store(p, v, __ATOMIC_RELAXED, __HIP_MEMORY_SCOPE_AGENT);
}

// 8x dwordx4 at 256B stride, sc0 (L1-bypass; L2-served when same-XCD).
__device__ __forceinline__ void ld8_sc0(u32x4 r[8], const u64* p) {
    asm volatile(
        "global_load_dwordx4 %0, %8, off sc0\n\t"
        "global_load_dwordx4 %1, %8, off offset:256 sc0\n\t"
        "global_load_dwordx4 %2, %8, off offset:512 sc0\n\t"
        "global_load_dwordx4 %3, %8, off offset:768 sc0\n\t"
        "global_load_dwordx4 %4, %8, off offset:1024 sc0\n\t"
        "global_load_dwordx4 %5, %8, off offset:1280 sc0\n\t"
        "global_load_dwordx4 %6, %8, off offset:1536 sc0\n\t"
        "global_load_dwordx4 %7, %8, off offset:1792 sc0\n\t"
        "s_waitcnt vmcnt(0)"
        : "=&v"(r[0]), "=&v"(r[1]), "=&v"(r[2]), "=&v"(r[3]),
          "=&v"(r[4]), "=&v"(r[5]), "=&v"(r[6]), "=&v"(r[7])
        : "v"(p)
        : "memory");
}

// ---------------------------------------------------------------------------
__global__ void setup_kernel(const float* __restrict__ X,
                             const float* __restrict__ hidden,
                             const float* __restrict__ b_hh,
                             const float* __restrict__ W_out,
                             const float* __restrict__ alpha_w,
                             const float* __restrict__ noise,
                             unsigned short* __restrict__ Xt,
                             float* __restrict__ NB,
                             unsigned short* __restrict__ Wo,
                             unsigned int* __restrict__ Hb0,
                             unsigned int* __restrict__ Hb1)
{
    int idx = blockIdx.x * 256 + threadIdx.x;
    // X [B][T][NIN] -> Xt [T][B][NIN] fp16
    if (idx < B_ * T_ * NIN) {
        int d = idx & 127, rest = idx >> 7;
        int brow = rest & 127, t = rest >> 7;
        Xt[idx] = f16bits(X[((size_t)brow * T_ + t) * NIN + d]);
    }
    if (idx < T_ * NH) {
        int c = idx & (NH - 1);
        NB[idx] = b_hh[c] + noise[idx] * (sqrtf(2.0f / alpha_w[c]) * SIGMA_F);
    }
    if (idx < NIN * NH) Wo[idx] = f16bits(W_out[idx]);
    if (idx < B_ * NH / 2) {
        // slot0 = initial h with gen-0 tag (0); slot1 = poison (tag 1)
        unsigned int lo = f16bits(hidden[idx * 2]);
        unsigned int hi = f16bits(hidden[idx * 2 + 1]);
        Hb0[idx] = (lo | (hi << 16)) & 0x7FFF7FFFu;
        Hb1[idx] = 0x80008000u;
    }
}

// ---------------------------------------------------------------------------
// Persistent RNN: 256 blocks x 256 threads (4 waves, 1 block/CU).
// Roles: m = bx&7 (batch group, XCD-striped), n = bx>>3 in [0,32) (col slice).
// Waves: c = wave&1 (col-tile of 16), kh = wave>>1 (K-half of 512).
__global__ __launch_bounds__(256, 1) void rnn_step_kernel(
    const float* __restrict__ W_hh, const float* __restrict__ W_in,
    const unsigned short* __restrict__ Xt, const float* __restrict__ NB,
    unsigned int* __restrict__ Hb0, unsigned int* __restrict__ Hb1,
    float* __restrict__ hidden_list, float* __restrict__ h_final)
{
    __shared__ unsigned short wtile[NCB * 1024];  // 65,536 B (32 rows x 1024)
    __shared__ unsigned short htile[16 * 1024];   // 32,768 B (group h tile)
    __shared__ f32x4 rtile[2][64];                //  2,048 B (split-K partials)

    const int tid = threadIdx.x;
    const int m = blockIdx.x & 7;    // batch group (XCD-striped)
    const int n = blockIdx.x >> 3;   // column slice [0,32)

    // ---- stage W slice (32 rows x 1024) into LDS, XOR-swizzled granules ----
    for (int g = tid; g < NCB * 128; g += 256) {
        int row = g >> 7, G = g & 127;
        const float* s = W_hh + (size_t)(n * NCB + row) * NH + G * 8;
        half8 h;
        #pragma unroll
        for (int j = 0; j < 8; ++j) h[j] = (_Float16)s[j];
        *(half8*)&wtile[row * 1024 + ((G ^ (row & 7)) << 3)] = h;
    }

    const int wave = tid >> 6, lane = tid & 63;
    const int c  = wave & 1;         // col-tile
    const int kh = wave >> 1;        // K-half
    const int l15 = lane & 15, lk = lane >> 4;
    const int colW = c * 16 + l15;          // local W row / output col
    const int gcol = n * NCB + colW;        // global hidden col

    // ---- per-lane register B-fragments for this wave's 2 x-chunks ----
    auto cvt8 = [](const float* s) {
        half8 h;
        #pragma unroll
        for (int j = 0; j < 8; ++j) h[j] = (_Float16)s[j];
        return h;
    };
    half8 bx2[2];
    #pragma unroll
    for (int j = 0; j < 2; ++j)
        bx2[j] = cvt8(W_in + (size_t)gcol * NIN + (2 * kh + j) * 32 + lk * 8);
    __syncthreads();   // wtile ready

    // h staging role: thread (hrow, part); 8 granules G=j*16+part of row hrow
    const int hrow = tid >> 4;       // 0..15
    const int part = tid & 15;

    const int rowA = m * MB + l15;

    auto xpart = [&](int t) -> f32x4 {
        f32x4 a = {0.f, 0.f, 0.f, 0.f};
        const half8* xp = (const half8*)(Xt + ((size_t)t * B_ + rowA) * NIN);
        #pragma unroll
        for (int j = 0; j < 2; ++j)
            a = __builtin_amdgcn_mfma_f32_16x16x32_f16(
                    xp[(2 * kh + j) * 4 + lk], bx2[j], a, 0, 0, 0);
        return a;
    };

    f32x4 accx = xpart(0);

    for (int t = 0; t < T_; ++t) {
        const u64* hp = (const u64*)((t & 1) ? Hb1 : Hb0)
                        + (size_t)(m * MB + hrow) * 256 + part * 2;
        const unsigned int e32 = ((t >> 1) & 1) ? 0x80008000u : 0u;

        // ---- phase 1: escalating tagged spin (cooperative, 128B/thread) ----
        u32x4 r[8];
        {
            int round = 0;
            for (;;) {
                if (round < 6) {
                    ld8_sc0(r, hp);
                } else {
                    #pragma unroll
                    for (int j = 0; j < 8; ++j) {
                        u64 a = ald(hp + (size_t)j * 32);
                        u64 b = ald(hp + (size_t)j * 32 + 1);
                        r[j][0] = (unsigned int)a; r[j][1] = (unsigned int)(a >> 32);
                        r[j][2] = (unsigned int)b; r[j][3] = (unsigned int)(b >> 32);
                    }
                }
                unsigned int red = 0;
                #pragma unroll
                for (int j = 0; j < 8; ++j) {
                    #pragma unroll
                    for (int k = 0; k < 4; ++k) red |= r[j][k] ^ e32;
                }
                if (!(red & 0x80008000u)) break;
                ++round;
                if (round >= 3) __builtin_amdgcn_s_sleep(1);
            }
        }

        __syncthreads();   // B1: all htile(t-1) reads complete (WAR)

        // strip tags, stage to LDS (swizzled granules)
        #pragma unroll
        for (int j = 0; j < 8; ++j) {
            u32x4 w;
            #pragma unroll
            for (int k = 0; k < 4; ++k) w[k] = r[j][k] & 0x7FFF7FFFu;
            int G = j * 16 + part;
            *(half8*)&htile[hrow * 1024 + ((G ^ (hrow & 7)) << 3)] =
                __builtin_bit_cast(half8, w);
        }

        __syncthreads();   // B2: htile ready

        // ---- phase 2: this wave's 16 k-chunks (K-half kh) for col-tile c ----
        f32x4 acc = accx;
        #pragma unroll
        for (int ki0 = 0; ki0 < 16; ++ki0) {
            int ki = 16 * kh + ki0;
            int G = 4 * ki + lk;
            half8 av = *(const half8*)&htile[l15 * 1024 + ((G ^ (l15 & 7)) << 3)];
            half8 bv = *(const half8*)&wtile[colW * 1024 + ((G ^ (colW & 7)) << 3)];
            acc = __builtin_amdgcn_mfma_f32_16x16x32_f16(av, bv, acc, 0, 0, 0);
        }

        // ---- split-K reduce: kh=1 writes partial, kh=0 combines ----
        if (kh == 1) rtile[c][lane] = acc;
        __syncthreads();   // B3: partials visible

        if (kh == 0) {
            f32x4 o = rtile[c][lane];
            const float nb = NB[t * NH + gcol];
            float hv[4];
            #pragma unroll
            for (int r2 = 0; r2 < 4; ++r2) {
                float v = acc[r2] + o[r2] + nb;
                hv[r2] = v > 0.f ? v : 0.f;
            }

            // publish h_{t+1} FIRST (tag in-word; agent store writes through
            // local L2 -> same-XCD sc0 pollers see it, L3 too)
            if (t < T_ - 1) {
                unsigned int* hn = (t & 1) ? Hb0 : Hb1;
                const unsigned int tagb = (((t + 1) >> 1) & 1) ? 0x80008000u : 0u;
                #pragma unroll
                for (int r2 = 0; r2 < 4; ++r2) {
                    float other = __shfl_xor(hv[r2], 1);
                    if (!(lane & 1)) {
                        unsigned int val = (unsigned int)f16bits(hv[r2]) |
                                           ((unsigned int)f16bits(other) << 16) | tagb;
                        int brow = m * MB + lk * 4 + r2;
                        ast(&hn[(size_t)brow * 512 + (gcol >> 1)], val);
                    }
                }
            }

            // off-critical-path: fp32 outputs (non-temporal, keep L2 clean)
            #pragma unroll
            for (int r2 = 0; r2 < 4; ++r2) {
                int brow = m * MB + lk * 4 + r2;
                __builtin_nontemporal_store(
                    hv[r2], &hidden_list[((size_t)brow * T_ + t) * NH + gcol]);
            }
            if (t == T_ - 1) {
                #pragma unroll
                for (int r2 = 0; r2 < 4; ++r2) {
                    int brow = m * MB + lk * 4 + r2;
                    __builtin_nontemporal_store(
                        hv[r2], &h_final[(size_t)brow * NH + gcol]);
                }
            }
        }
        if (t < T_ - 1) accx = xpart(t + 1);
    }
}

// ---------------------------------------------------------------------------
// Readout: Y[32768,128] = HL[32768,1024](f32->f16) @ Wo^T(f16), fp32 out.
__global__ __launch_bounds__(256, 4) void ygemm_kernel(
    const float* __restrict__ HL, const unsigned short* __restrict__ Wo,
    float* __restrict__ Y)
{
    typedef unsigned short ushort8 __attribute__((ext_vector_type(8)));
    const int tid = threadIdx.x;
    const int wave = tid >> 6, lane = tid & 63;
    const int l15 = lane & 15, lk = lane >> 4;
    const size_t rowbase = (size_t)blockIdx.x * 64;

    f32x4 acc[4][2] = {};

    #pragma unroll 2
    for (int ki = 0; ki < 32; ++ki) {
        const int k0 = ki * 32 + lk * 8;
        half8 bfr[2];
        #pragma unroll
        for (int nt = 0; nt < 2; ++nt) {
            int ncol = (wave * 2 + nt) * 16 + l15;
            ushort8 braw = *(const ushort8*)(Wo + ncol * NH + k0);
            bfr[nt] = __builtin_bit_cast(half8, braw);
        }
        #pragma unroll
        for (int mt = 0; mt < 4; ++mt) {
            size_t row = rowbase + mt * 16 + l15;
            const float4* ap = (const float4*)(HL + row * NH + k0);
            float4 a0 = ap[0];
            float4 a1 = ap[1];
            half8 a = { (_Float16)a0.x, (_Float16)a0.y, (_Float16)a0.z, (_Float16)a0.w,
                        (_Float16)a1.x, (_Float16)a1.y, (_Float16)a1.z, (_Float16)a1.w };
            #pragma unroll
            for (int nt = 0; nt < 2; ++nt)
                acc[mt][nt] = __builtin_amdgcn_mfma_f32_16x16x32_f16(a, bfr[nt], acc[mt][nt], 0, 0, 0);
        }
    }

    #pragma unroll
    for (int mt = 0; mt < 4; ++mt) {
        #pragma unroll
        for (int nt = 0; nt < 2; ++nt) {
            int ncol = (wave * 2 + nt) * 16 + l15;
            #pragma unroll
            for (int r = 0; r < 4; ++r) {
                size_t row = rowbase + mt * 16 + lk * 4 + r;
                Y[row * NIN + ncol] = acc[mt][nt][r];
            }
        }
    }
}

// ---------------------------------------------------------------------------
extern "C" void kernel_launch(void* const* d_in, const int* in_sizes, int n_in,
                              void* d_out, int out_size, void* d_ws, size_t ws_size,
                              hipStream_t stream)
{
    const float* X      = (const float*)d_in[0];
    const float* hidden = (const float*)d_in[1];
    const float* W_in   = (const float*)d_in[2];
    const float* W_hh   = (const float*)d_in[3];
    const float* b_hh   = (const float*)d_in[4];
    const float* W_out  = (const float*)d_in[5];
    const float* alpha  = (const float*)d_in[6];
    const float* noise  = (const float*)d_in[7];

    char* ws = (char*)d_ws;   // ~10.2 MB
    unsigned short* Xt = (unsigned short*)(ws + OFF_XT);
    float*          NB = (float*)(ws + OFF_NB);
    unsigned short* Wo = (unsigned short*)(ws + OFF_WO);
    unsigned int*  Hb0 = (unsigned int*)(ws + OFF_HB);
    unsigned int*  Hb1 = Hb0 + (size_t)B_ * NH / 2;

    float* hidden_list = (float*)d_out;                                  // [128,256,1024]
    float* output_list = hidden_list + (size_t)B_ * T_ * NH;             // [128,256,128]
    float* h_final     = output_list + (size_t)B_ * T_ * NIN;            // [128,1024]

    setup_kernel<<<(B_ * T_ * NIN + 255) / 256, 256, 0, stream>>>(
        X, hidden, b_hh, W_out, alpha, noise, Xt, NB, Wo, Hb0, Hb1);

    rnn_step_kernel<<<256, 256, 0, stream>>>(
        W_hh, W_in, Xt, NB, Hb0, Hb1, hidden_list, h_final);

    ygemm_kernel<<<(B_ * T_) / 64, 256, 0, stream>>>(
        hidden_list, Wo, output_list);
}

// Round 12
// 923.014 us; speedup vs baseline: 7.8649x; 1.9128x over previous
//
#include <hip/hip_runtime.h>
#include <hip/hip_fp16.h>
#include <math.h>

// ---------------------------------------------------------------------------
// RNN: h_{t+1} = relu(x_t @ W_in^T + h_t @ W_hh^T + b_hh + noise_t*scale)
// outputs: hidden_list [128,256,1024] f32, output_list [128,256,128] f32,
//          h_final [128,1024] f32 (concatenated flat in d_out)
//
// R12 = R9 exchange (XCD-striped, sc0 L2 spin + escalation; FETCH 298->59MB
// proven) + DIRECT-TO-VGPR A-fragments done right:
//  - R10 failed on (a) 128 live VGPRs -> spill, (b) uncoalesced L2 gathers.
//    R11 failed by duplicating input traffic (2x blocks, same h).
//  - Fix (a): chunk K into 4x8 k-frags; only q[8]=32 VGPR live at a time.
//  - Fix (b): FRAGMENT-MAJOR h layout Hf[slot][m][ki][lk][row]x16B: a wave's
//    8 chunk loads = contiguous 1KB -> perfect coalescing.
//  - No htile, no LDS staging, no av ds_reads, NO barriers in time loop.
//  - Sign trick (R10-proven): tag bit == fp16 sign, relu(h)>=0 => tagged
//    tile = -h. h-part in own acc, combined with sg=+/-1 fmaf. No stripping.
//  - Exchange: publish = agent-relaxed u32 stores into consumers' fragment
//    slots; spin = sc0 chunk loads (L2-served same-XCD), escalate to
//    sc0 sc1 (coherence point) after ~20 rounds -> liveness under ANY
//    blockIdx->XCD mapping. Gen-tag ring (t>>1)&1, 2 slots. WAR safe at
//    wave granularity: wave publishes h(t+1) only after reading ALL K of
//    h(t); h(t+2) writers need all of h(t+1) -> transitively safe.
//  - W: full 64x1024 fp16 slice in LDS (128KB, XOR-swizzled granules).
//    Per-wave LDS reads drop 62->32 (bv only), conflicts <=2-way.
// ---------------------------------------------------------------------------

typedef _Float16 half8 __attribute__((ext_vector_type(8)));
typedef float    f32x4 __attribute__((ext_vector_type(4)));
typedef unsigned int u32x4 __attribute__((ext_vector_type(4)));
typedef unsigned long long u64;

#define SIGMA_F 0.05f

constexpr int T_  = 256;
constexpr int B_  = 128;
constexpr int NH  = 1024;
constexpr int NIN = 128;
constexpr int MB  = 16;           // batch rows per group

// workspace layout (bytes)
constexpr size_t OFF_XT  = 0;                            // fp16 [T][B][NIN] 8.39MB
constexpr size_t OFF_NB  = (size_t)T_*B_*NIN*2;          // f32  [T][NH]     1.05MB
constexpr size_t OFF_WO  = OFF_NB + (size_t)T_*NH*4;     // fp16 [NIN][NH]   0.26MB
constexpr size_t OFF_HB  = OFF_WO + (size_t)NIN*NH*2;    // u32 [2][8][8192] 0.52MB

__device__ __forceinline__ unsigned short f16bits(float v) {
    return __half_as_ushort(__float2half(v));
}
__device__ __forceinline__ void ast(unsigned int* p, unsigned int v) {
    __hip_atomic_store(p, v, __ATOMIC_RELAXED, __HIP_MEMORY_SCOPE_AGENT);
}

// one k-chunk = 8 contiguous KB-coalesced dwordx4 frags (1KB apart per ki).
// p2 = p + 4096 (13-bit imm offset limit). Tail vmcnt(0) self-contains deps.
__device__ __forceinline__ void ld_chunk_sc0(u32x4 q[8], const char* p,
                                             const char* p2) {
    asm volatile(
        "global_load_dwordx4 %0, %8, off sc0\n\t"
        "global_load_dwordx4 %1, %8, off offset:1024 sc0\n\t"
        "global_load_dwordx4 %2, %8, off offset:2048 sc0\n\t"
        "global_load_dwordx4 %3, %8, off offset:3072 sc0\n\t"
        "global_load_dwordx4 %4, %9, off sc0\n\t"
        "global_load_dwordx4 %5, %9, off offset:1024 sc0\n\t"
        "global_load_dwordx4 %6, %9, off offset:2048 sc0\n\t"
        "global_load_dwordx4 %7, %9, off offset:3072 sc0\n\t"
        "s_waitcnt vmcnt(0)"
        : "=&v"(q[0]), "=&v"(q[1]), "=&v"(q[2]), "=&v"(q[3]),
          "=&v"(q[4]), "=&v"(q[5]), "=&v"(q[6]), "=&v"(q[7])
        : "v"(p), "v"(p2)
        : "memory");
}
__device__ __forceinline__ void ld_chunk_sys(u32x4 q[8], const char* p,
                                             const char* p2) {
    asm volatile(
        "global_load_dwordx4 %0, %8, off sc0 sc1\n\t"
        "global_load_dwordx4 %1, %8, off offset:1024 sc0 sc1\n\t"
        "global_load_dwordx4 %2, %8, off offset:2048 sc0 sc1\n\t"
        "global_load_dwordx4 %3, %8, off offset:3072 sc0 sc1\n\t"
        "global_load_dwordx4 %4, %9, off sc0 sc1\n\t"
        "global_load_dwordx4 %5, %9, off offset:1024 sc0 sc1\n\t"
        "global_load_dwordx4 %6, %9, off offset:2048 sc0 sc1\n\t"
        "global_load_dwordx4 %7, %9, off offset:3072 sc0 sc1\n\t"
        "s_waitcnt vmcnt(0)"
        : "=&v"(q[0]), "=&v"(q[1]), "=&v"(q[2]), "=&v"(q[3]),
          "=&v"(q[4]), "=&v"(q[5]), "=&v"(q[6]), "=&v"(q[7])
        : "v"(p), "v"(p2)
        : "memory");
}

// ---------------------------------------------------------------------------
__global__ void setup_kernel(const float* __restrict__ X,
                             const float* __restrict__ hidden,
                             const float* __restrict__ b_hh,
                             const float* __restrict__ W_out,
                             const float* __restrict__ alpha_w,
                             const float* __restrict__ noise,
                             unsigned short* __restrict__ Xt,
                             float* __restrict__ NB,
                             unsigned short* __restrict__ Wo,
                             unsigned int* __restrict__ Hb0,
                             unsigned int* __restrict__ Hb1)
{
    int idx = blockIdx.x * 256 + threadIdx.x;
    // X [B][T][NIN] -> Xt [T][B][NIN] fp16
    if (idx < B_ * T_ * NIN) {
        int d = idx & 127, rest = idx >> 7;
        int brow = rest & 127, t = rest >> 7;
        Xt[idx] = f16bits(X[((size_t)brow * T_ + t) * NIN + d]);
    }
    if (idx < T_ * NH) {
        int c = idx & (NH - 1);
        NB[idx] = b_hh[c] + noise[idx] * (sqrtf(2.0f / alpha_w[c]) * SIGMA_F);
    }
    if (idx < NIN * NH) Wo[idx] = f16bits(W_out[idx]);
    // Hf fragment-major: u32 idx -> (m, ki, lk, r, elem-pair)
    if (idx < B_ * NH / 2) {
        int m2   = idx >> 13;          // 8192 u32 per group
        int rest = idx & 8191;
        int kilk = rest >> 6;          // (ki*4+lk) in 0..127
        int r    = (rest >> 2) & 15;
        int ep   = rest & 3;
        int ki = kilk >> 2, lkq = kilk & 3;
        int col  = ki * 32 + lkq * 8 + ep * 2;
        int brow = m2 * 16 + r;
        unsigned int lo = f16bits(hidden[(size_t)brow * NH + col]);
        unsigned int hi = f16bits(hidden[(size_t)brow * NH + col + 1]);
        Hb0[idx] = (lo | (hi << 16)) & 0x7FFF7FFFu;  // gen-0 tag (0)
        Hb1[idx] = 0x80008000u;                      // poison (tag 1)
    }
}

// ---------------------------------------------------------------------------
// Persistent RNN: 128 blocks x 256 threads (4 waves, 1 block/CU).
// Roles: m = bx&7 (batch group, XCD-striped), n = bx>>3 (64-col slice).
// Wave owns 16 cols; NO barriers, NO LDS h-path in the time loop.
__global__ __launch_bounds__(256, 1) void rnn_step_kernel(
    const float* __restrict__ W_hh, const float* __restrict__ W_in,
    const unsigned short* __restrict__ Xt, const float* __restrict__ NB,
    unsigned int* __restrict__ Hb0, unsigned int* __restrict__ Hb1,
    float* __restrict__ hidden_list, float* __restrict__ h_final)
{
    __shared__ unsigned short wtile[64 * 1024];   // 131,072 B: full W slice

    const int tid = threadIdx.x;
    const int m = blockIdx.x & 7;    // batch group (XCD-striped)
    const int n = blockIdx.x >> 3;   // column slice

    // ---- stage W slice (64 rows x 1024) into LDS, XOR-swizzled granules ----
    for (int g = tid; g < 64 * 128; g += 256) {
        int row = g >> 7, G = g & 127;
        const float* s = W_hh + (size_t)(n * 64 + row) * NH + G * 8;
        half8 h;
        #pragma unroll
        for (int j = 0; j < 8; ++j) h[j] = (_Float16)s[j];
        *(half8*)&wtile[row * 1024 + ((G ^ (row & 7)) << 3)] = h;
    }

    const int wave = tid >> 6, lane = tid & 63;
    const int l15 = lane & 15, lk = lane >> 4;
    const int rowA = m * MB + l15;
    const int colW = wave * 16 + l15;       // local W row / output col
    const int gcol = n * 64 + colW;         // global hidden col

    // ---- per-lane register B-fragments for the x-part (4 chunks) ----
    auto cvt8 = [](const float* s) {
        half8 h;
        #pragma unroll
        for (int j = 0; j < 8; ++j) h[j] = (_Float16)s[j];
        return h;
    };
    half8 bx[4];
    #pragma unroll
    for (int kx = 0; kx < 4; ++kx)
        bx[kx] = cvt8(W_in + (size_t)gcol * NIN + kx * 32 + lk * 8);
    __syncthreads();   // wtile ready (only barrier in the kernel)

    auto xpart = [&](int t) -> f32x4 {
        f32x4 a = {0.f, 0.f, 0.f, 0.f};
        const half8* xp = (const half8*)(Xt + ((size_t)t * B_ + rowA) * NIN) + lk;
        #pragma unroll
        for (int kx = 0; kx < 4; ++kx)
            a = __builtin_amdgcn_mfma_f32_16x16x32_f16(xp[kx * 4], bx[kx], a, 0, 0, 0);
        return a;
    };

    // consumer per-lane fragment base (within a slot): group m, lk, row l15
    const size_t consOff = (size_t)m * 32768 + lk * 256 + l15 * 16;
    // producer per-lane u32 offset (within a slot), even lanes only:
    // frag(ki=gcol>>5, lkc=(gcol>>3)&3), row = lk*4+r2, elem = gcol&7
    const size_t pubOff = (size_t)m * 32768
                        + (((gcol >> 5) * 4 + ((gcol >> 3) & 3)) << 8)
                        + lk * 64 + (gcol & 7) * 2;

    f32x4 accx = xpart(0);

    for (int t = 0; t < T_; ++t) {
        const char* hsrc = (const char*)((t & 1) ? Hb1 : Hb0) + consOff;
        const bool tagset = ((t >> 1) & 1) != 0;
        const unsigned int e32 = tagset ? 0x80008000u : 0u;

        f32x4 acc0 = {0.f, 0.f, 0.f, 0.f}, acc1 = {0.f, 0.f, 0.f, 0.f};
        int esc = 0;

        #pragma unroll
        for (int c2 = 0; c2 < 4; ++c2) {
            const char* pc = hsrc + c2 * 8192;
            u32x4 q[8];
            ld_chunk_sc0(q, pc, pc + 4096);
            // tagged validation; batched parallel retry with escalation
            for (;;) {
                u32x4 e4 = {e32, e32, e32, e32};
                u32x4 red4 = q[0] ^ e4;
                #pragma unroll
                for (int j = 1; j < 8; ++j) red4 |= q[j] ^ e4;
                unsigned int red = red4[0] | red4[1] | red4[2] | red4[3];
                if (!(red & 0x80008000u)) break;
                ++esc;
                if (esc > 6)  __builtin_amdgcn_s_sleep(1);
                if (esc < 20) ld_chunk_sc0(q, pc, pc + 4096);
                else          ld_chunk_sys(q, pc, pc + 4096);  // liveness
            }
            // 8 MFMAs: av straight from regs (sign-tagged), bv from LDS
            #pragma unroll
            for (int j = 0; j < 8; ++j) {
                int ki = c2 * 8 + j;
                int G = 4 * ki + lk;
                half8 bv = *(const half8*)&wtile[colW * 1024 + ((G ^ (colW & 7)) << 3)];
                half8 av = __builtin_bit_cast(half8, q[j]);
                if (j & 1) acc1 = __builtin_amdgcn_mfma_f32_16x16x32_f16(av, bv, acc1, 0, 0, 0);
                else       acc0 = __builtin_amdgcn_mfma_f32_16x16x32_f16(av, bv, acc0, 0, 0, 0);
            }
        }

        // ---- bias+noise, sign-compensated combine, relu ----
        const float nb = NB[t * NH + gcol];
        const float sg = tagset ? -1.f : 1.f;
        float hv[4];
        #pragma unroll
        for (int r2 = 0; r2 < 4; ++r2) {
            float v = fmaf(sg, acc0[r2] + acc1[r2], accx[r2] + nb);
            hv[r2] = v > 0.f ? v : 0.f;
        }

        // ---- publish h_{t+1} FIRST (tag in-word, fragment-major slots) ----
        if (t < T_ - 1) {
            unsigned int* hn = (t & 1) ? Hb0 : Hb1;
            const unsigned int tagb = (((t + 1) >> 1) & 1) ? 0x80008000u : 0u;
            #pragma unroll
            for (int r2 = 0; r2 < 4; ++r2) {
                float other = __shfl_xor(hv[r2], 1);
                if (!(lane & 1)) {
                    unsigned int val = (unsigned int)f16bits(hv[r2]) |
                                       ((unsigned int)f16bits(other) << 16) | tagb;
                    ast((unsigned int*)((char*)hn + pubOff + r2 * 16), val);
                }
            }
        }

        // ---- off-critical-path: fp32 outputs, next x-part ----
        #pragma unroll
        for (int r2 = 0; r2 < 4; ++r2) {
            int brow = m * MB + lk * 4 + r2;
            hidden_list[((size_t)brow * T_ + t) * NH + gcol] = hv[r2];
        }
        if (t == T_ - 1) {
            #pragma unroll
            for (int r2 = 0; r2 < 4; ++r2) {
                int brow = m * MB + lk * 4 + r2;
                h_final[(size_t)brow * NH + gcol] = hv[r2];
            }
        } else {
            accx = xpart(t + 1);
        }
    }
}

// ---------------------------------------------------------------------------
// Readout: Y[32768,128] = HL[32768,1024](f32->f16) @ Wo^T(f16), fp32 out.
__global__ __launch_bounds__(256, 4) void ygemm_kernel(
    const float* __restrict__ HL, const unsigned short* __restrict__ Wo,
    float* __restrict__ Y)
{
    typedef unsigned short ushort8 __attribute__((ext_vector_type(8)));
    const int tid = threadIdx.x;
    const int wave = tid >> 6, lane = tid & 63;
    const int l15 = lane & 15, lk = lane >> 4;
    const size_t rowbase = (size_t)blockIdx.x * 64;

    f32x4 acc[4][2] = {};

    #pragma unroll 2
    for (int ki = 0; ki < 32; ++ki) {
        const int k0 = ki * 32 + lk * 8;
        half8 bfr[2];
        #pragma unroll
        for (int nt = 0; nt < 2; ++nt) {
            int ncol = (wave * 2 + nt) * 16 + l15;
            ushort8 braw = *(const ushort8*)(Wo + ncol * NH + k0);
            bfr[nt] = __builtin_bit_cast(half8, braw);
        }
        #pragma unroll
        for (int mt = 0; mt < 4; ++mt) {
            size_t row = rowbase + mt * 16 + l15;
            const float4* ap = (const float4*)(HL + row * NH + k0);
            float4 a0 = ap[0];
            float4 a1 = ap[1];
            half8 a = { (_Float16)a0.x, (_Float16)a0.y, (_Float16)a0.z, (_Float16)a0.w,
                        (_Float16)a1.x, (_Float16)a1.y, (_Float16)a1.z, (_Float16)a1.w };
            #pragma unroll
            for (int nt = 0; nt < 2; ++nt)
                acc[mt][nt] = __builtin_amdgcn_mfma_f32_16x16x32_f16(a, bfr[nt], acc[mt][nt], 0, 0, 0);
        }
    }

    #pragma unroll
    for (int mt = 0; mt < 4; ++mt) {
        #pragma unroll
        for (int nt = 0; nt < 2; ++nt) {
            int ncol = (wave * 2 + nt) * 16 + l15;
            #pragma unroll
            for (int r = 0; r < 4; ++r) {
                size_t row = rowbase + mt * 16 + lk * 4 + r;
                Y[row * NIN + ncol] = acc[mt][nt][r];
            }
        }
    }
}

// ---------------------------------------------------------------------------
extern "C" void kernel_launch(void* const* d_in, const int* in_sizes, int n_in,
                              void* d_out, int out_size, void* d_ws, size_t ws_size,
                              hipStream_t stream)
{
    const float* X      = (const float*)d_in[0];
    const float* hidden = (const float*)d_in[1];
    const float* W_in   = (const float*)d_in[2];
    const float* W_hh   = (const float*)d_in[3];
    const float* b_hh   = (const float*)d_in[4];
    const float* W_out  = (const float*)d_in[5];
    const float* alpha  = (const float*)d_in[6];
    const float* noise  = (const float*)d_in[7];

    char* ws = (char*)d_ws;   // ~10.2 MB
    unsigned short* Xt = (unsigned short*)(ws + OFF_XT);
    float*          NB = (float*)(ws + OFF_NB);
    unsigned short* Wo = (unsigned short*)(ws + OFF_WO);
    unsigned int*  Hb0 = (unsigned int*)(ws + OFF_HB);
    unsigned int*  Hb1 = Hb0 + (size_t)B_ * NH / 2;

    float* hidden_list = (float*)d_out;                                  // [128,256,1024]
    float* output_list = hidden_list + (size_t)B_ * T_ * NH;             // [128,256,128]
    float* h_final     = output_list + (size_t)B_ * T_ * NIN;            // [128,1024]

    setup_kernel<<<(B_ * T_ * NIN + 255) / 256, 256, 0, stream>>>(
        X, hidden, b_hh, W_out, alpha, noise, Xt, NB, Wo, Hb0, Hb1);

    rnn_step_kernel<<<128, 256, 0, stream>>>(
        W_hh, W_in, Xt, NB, Hb0, Hb1, hidden_list, h_final);

    ygemm_kernel<<<(B_ * T_) / 64, 256, 0, stream>>>(
        hidden_list, Wo, output_list);
}